// Round 4
// baseline (4534.714 us; speedup 1.0000x reference)
//
#include <hip/hip_runtime.h>
#include <hip/hip_bf16.h>
#include <stdint.h>

#define BB   64
#define TT   2048
#define II   256
#define HH   256
#define G4   1024   // 4*H
#define NC   10

typedef _Float16 half2v __attribute__((ext_vector_type(2)));
typedef _Float16 half8v __attribute__((ext_vector_type(8)));
typedef float    float4v __attribute__((ext_vector_type(4)));

__device__ __forceinline__ float sigmf(float v) { return 1.f / (1.f + __expf(-v)); }
__device__ __forceinline__ float tanhf2(float v) { float e = __expf(2.f * v); return 1.f - 2.f / (e + 1.f); }

// Barrier WITHOUT vmcnt drain: keeps the global xpk prefetch in flight.
__device__ __forceinline__ void bar_lds() {
  asm volatile("s_waitcnt lgkmcnt(0)\n\ts_barrier" ::: "memory");
}

// ---------------------------------------------------------------------------
// K0a: WcT[g][i] = sum_j key[i][j] * W_ih[g][j]  (f16), biasc[g] = b_ih+b_hh
// ---------------------------------------------------------------------------
__global__ __launch_bounds__(1024) void prep_wc(
    const float* __restrict__ key, const float* __restrict__ Wih,
    const float* __restrict__ bih, const float* __restrict__ bhh,
    _Float16* __restrict__ WcT, float* __restrict__ biasc) {
  __shared__ float krow[II];
  const int i = blockIdx.x;
  const int g = threadIdx.x;
  if (g < II) krow[g] = key[(size_t)i * II + g];
  __syncthreads();
  const float4* w4 = (const float4*)(Wih + (size_t)g * II);
  float acc = 0.f;
#pragma unroll 8
  for (int j = 0; j < II / 4; ++j) {
    float4 w = w4[j];
    acc += w.x * krow[4 * j] + w.y * krow[4 * j + 1] + w.z * krow[4 * j + 2] + w.w * krow[4 * j + 3];
  }
  WcT[(size_t)g * II + i] = (_Float16)acc;
  if (i == 0) biasc[g] = bih[g] + bhh[g];
}

// ---------------------------------------------------------------------------
// K0c: pack W_hh into MFMA A-fragment order (f16) for lstm_seq.
// mfma_f32_16x16x32_f16 A-fragment (same mapping as the passing gemm_xproj):
//   lane holds 8 f16: row = lane&15 (within 16-row tile), k = (lane>>4)*8+jj.
// Wave w of lstm_seq owns gate rows w*128 + m*16 + rowInTile, m = 0..7.
// K-tiles kt 0..5 -> wreg (register-resident), kt 6..7 -> wldsG (LDS tail).
// Fragment linear index: [kt|kt-6][w][m][lane] * 16 B.
// ---------------------------------------------------------------------------
__global__ __launch_bounds__(256) void prep_wfrag(
    const float* __restrict__ Whh, uint4* __restrict__ wreg, uint4* __restrict__ wldsG) {
  const int id = blockIdx.x * 256 + threadIdx.x;   // 32768 = 8kt*8w*8m*64lane
  const int lane = id & 63;
  const int m  = (id >> 6) & 7;
  const int w  = (id >> 9) & 7;
  const int kt = (id >> 12) & 7;
  const int row = w * 128 + m * 16 + (lane & 15);
  const int k0  = kt * 32 + (lane >> 4) * 8;
  half8v frag;
#pragma unroll
  for (int jj = 0; jj < 8; ++jj) frag[jj] = (_Float16)Whh[(size_t)row * HH + k0 + jj];
  uint4 u = __builtin_bit_cast(uint4, frag);
  if (kt < 6) wreg[((kt * 8 + w) * 8 + m) * 64 + lane] = u;
  else        wldsG[(((kt - 6) * 8 + w) * 8 + m) * 64 + lane] = u;
}

// ---------------------------------------------------------------------------
// K1: packed x-projection GEMM. Logical x_proj[m][g]; stored so lstm thread j
// reads ONE dwordx2: f16 slot (col&255)*4 + (col>>8) within the m-row, i.e.
// uint2[j] = ((xi,xf),(xg,xo)) for h-element j.
// ---------------------------------------------------------------------------
__global__ __launch_bounds__(256) void gemm_xproj(
    const float* __restrict__ x, const _Float16* __restrict__ WcT,
    const float* __restrict__ biasc, _Float16* __restrict__ xpk) {
  __shared__ __align__(16) _Float16 Asm[128][40];
  __shared__ __align__(16) _Float16 Bsm[128][40];
  const int t = threadIdx.x;
  const int n0 = blockIdx.x * 128;
  const int m0 = blockIdx.y * 128;
  const int r = t >> 1;
  const int hoff = (t & 1) * 16;
  const int lane = t & 63, wave = t >> 6;
  const int quad = lane >> 4, l15 = lane & 15;
  const int mh = (wave & 1) * 64, nh = (wave >> 1) * 64;
  float4v zero = {0.f, 0.f, 0.f, 0.f};
  float4v acc[4][4];
#pragma unroll
  for (int a = 0; a < 4; ++a)
#pragma unroll
    for (int b = 0; b < 4; ++b) acc[a][b] = zero;

  for (int kt = 0; kt < 8; ++kt) {
    const int k0 = kt * 32;
    const float4* xa = (const float4*)(x + (size_t)(m0 + r) * II + k0 + hoff);
    float4 f0 = xa[0], f1 = xa[1], f2 = xa[2], f3 = xa[3];
    half8v lo = {(_Float16)f0.x, (_Float16)f0.y, (_Float16)f0.z, (_Float16)f0.w,
                 (_Float16)f1.x, (_Float16)f1.y, (_Float16)f1.z, (_Float16)f1.w};
    half8v hi = {(_Float16)f2.x, (_Float16)f2.y, (_Float16)f2.z, (_Float16)f2.w,
                 (_Float16)f3.x, (_Float16)f3.y, (_Float16)f3.z, (_Float16)f3.w};
    const half8v* bsrc = (const half8v*)(WcT + (size_t)(n0 + r) * II + k0 + hoff);
    half8v b0 = bsrc[0], b1 = bsrc[1];
    *(half8v*)&Asm[r][hoff]     = lo;
    *(half8v*)&Asm[r][hoff + 8] = hi;
    *(half8v*)&Bsm[r][hoff]     = b0;
    *(half8v*)&Bsm[r][hoff + 8] = b1;
    __syncthreads();
    half8v af[4], bf[4];
#pragma unroll
    for (int mt = 0; mt < 4; ++mt) af[mt] = *(const half8v*)&Asm[mh + mt * 16 + l15][quad * 8];
#pragma unroll
    for (int nt = 0; nt < 4; ++nt) bf[nt] = *(const half8v*)&Bsm[nh + nt * 16 + l15][quad * 8];
#pragma unroll
    for (int mt = 0; mt < 4; ++mt)
#pragma unroll
      for (int nt = 0; nt < 4; ++nt)
        acc[mt][nt] = __builtin_amdgcn_mfma_f32_16x16x32_f16(af[mt], bf[nt], acc[mt][nt], 0, 0, 0);
    __syncthreads();
  }
  _Float16* dst = xpk;
#pragma unroll
  for (int nt = 0; nt < 4; ++nt) {
    const int col = n0 + nh + nt * 16 + l15;
    const float bias = biasc[col];
    const int slot16 = (col & 255) * 4 + (col >> 8);
#pragma unroll
    for (int mt = 0; mt < 4; ++mt) {
      const int mrow = m0 + mh + mt * 16 + quad * 4;
#pragma unroll
      for (int j = 0; j < 4; ++j)
        dst[(size_t)(mrow + j) * 1024 + slot16] = (_Float16)(acc[mt][nt][j] + bias);
    }
  }
}

// ---------------------------------------------------------------------------
// K2: sequential LSTM on the MFMA pipe.
// 512 threads (8 waves, 2/SIMD, 256 unified regs). Wave w owns gate rows
// w*128..w*128+127 (8 M-tiles of 16). Per step, per wave:
//   y_tile[16] = sum_kt A(W frag) x B(h replicated across 16 cols), 64 MFMA.
//   - A for kt 0..5 in registers (192 regs; AGPR-eligible, MFMA reads AGPRs
//     directly -> no copy tax, unlike v_dot2)
//   - A for kt 6..7 from LDS (128 KB, fragment-order -> conflict-free b128)
//   - B-frag: value depends only on k=quad*8+j -> ONE ds_read_b128 of the
//     512 B h vector per K-tile (broadcast, 4 distinct addrs) replaces the
//     old 128 v_readlane/thread
//   - D columns all equal y; lanes (lane&15)==0 hold y[quad*4+reg] ->
//     masked ds_write_b128 to gates_lds
// Epilogue (threads<256): 4 ds_read_b32 gates + xpk dwordx2 ((xi,xf),(xg,xo)),
// thread-local c/h update, h write (f16). Two barriers/step, no vmcnt drain.
// ---------------------------------------------------------------------------
__global__ __launch_bounds__(512, 2) void lstm_seq(
    const uint32_t* __restrict__ xpk, const uint4* __restrict__ wreg,
    const uint4* __restrict__ wldsG, float* __restrict__ hfin) {
  __shared__ __align__(16) _Float16 wsmh[2 * 8 * 8 * 64 * 8];  // 128 KB A-tail
  __shared__ __align__(16) _Float16 hsh[256];                  // h (f16)
  __shared__ __align__(16) float gsh[G4];                      // y (gates)
  const int t0 = threadIdx.x, b = blockIdx.x;
  const int w = t0 >> 6, lane = t0 & 63, quad = lane >> 4;

  half8v wA[48];                                   // kt 0..5 x m 0..7
#pragma unroll
  for (int kt = 0; kt < 6; ++kt)
#pragma unroll
    for (int m = 0; m < 8; ++m)
      wA[kt * 8 + m] = __builtin_bit_cast(half8v, wreg[((kt * 8 + w) * 8 + m) * 64 + lane]);
#pragma unroll
  for (int i = 0; i < 16; ++i)
    ((uint4*)wsmh)[i * 512 + t0] = wldsG[i * 512 + t0];
  if (t0 < 128) ((uint32_t*)hsh)[t0] = 0;

  float cst = 0.f, hlast = 0.f;
  const uint2* xq = (const uint2*)xpk + (size_t)b * TT * 256 + t0;  // t0<256 only
  uint2 xn = {0u, 0u};
  if (t0 < 256) xn = xq[0];
  __syncthreads();

  const float4v zero = {0.f, 0.f, 0.f, 0.f};
  for (int t = 0; t < TT; ++t) {
    const uint2 xw = xn;
    if (t0 < 256) xn = xq[(size_t)((t + 1) & (TT - 1)) * 256];  // prefetch
    float4v acc[8];
#pragma unroll
    for (int kt = 0; kt < 8; ++kt) {
      half8v bf = *(const half8v*)&hsh[kt * 32 + quad * 8];     // broadcast
      if (kt < 6) {
#pragma unroll
        for (int m = 0; m < 8; ++m)
          acc[m] = __builtin_amdgcn_mfma_f32_16x16x32_f16(
              wA[kt * 8 + m], bf, (kt == 0) ? zero : acc[m], 0, 0, 0);
      } else {
#pragma unroll
        for (int m = 0; m < 8; ++m) {
          half8v wf = *(const half8v*)&wsmh[((((kt - 6) * 8 + w) * 8 + m) * 64 + lane) * 8];
          acc[m] = __builtin_amdgcn_mfma_f32_16x16x32_f16(wf, bf, acc[m], 0, 0, 0);
        }
      }
    }
    if ((lane & 15) == 0) {                        // col-0 lanes hold y
#pragma unroll
      for (int m = 0; m < 8; ++m)
        *(float4v*)&gsh[w * 128 + m * 16 + quad * 4] = acc[m];
    }
    bar_lds();
    if (t0 < 256) {
      float gi = gsh[t0], gf = gsh[t0 + 256], gg = gsh[t0 + 512], go = gsh[t0 + 768];
      half2v xa = __builtin_bit_cast(half2v, xw.x);   // (xi, xf)
      half2v xb = __builtin_bit_cast(half2v, xw.y);   // (xg, xo)
      float ig = sigmf(gi + (float)xa.x);
      float fg = sigmf(gf + (float)xa.y);
      float g2 = tanhf2(gg + (float)xb.x);
      float og = sigmf(go + (float)xb.y);
      cst = fg * cst + ig * g2;
      hlast = og * tanhf2(cst);
      hsh[t0] = (_Float16)hlast;
    }
    bar_lds();
  }
  if (t0 < 256) hfin[(size_t)b * HH + t0] = hlast;
}

// ---------------------------------------------------------------------------
// K3: out[b][c] = h_last[b] . W_cls[c] + b_cls[c]
// ---------------------------------------------------------------------------
__global__ __launch_bounds__(256) void cls_k(
    const float* __restrict__ hfin, const float* __restrict__ Wcls,
    const float* __restrict__ bcls, float* __restrict__ out) {
  __shared__ float part[4][NC];
  const int b = blockIdx.x, tid = threadIdx.x;
  const int lane = tid & 63, wave = tid >> 6;
  float hv = hfin[(size_t)b * HH + tid];
#pragma unroll
  for (int c = 0; c < NC; ++c) {
    float p = hv * Wcls[c * HH + tid];
#pragma unroll
    for (int off = 32; off >= 1; off >>= 1) p += __shfl_down(p, off, 64);
    if (lane == 0) part[wave][c] = p;
  }
  __syncthreads();
  if (tid < NC) {
    out[(size_t)b * NC + tid] =
        part[0][tid] + part[1][tid] + part[2][tid] + part[3][tid] + bcls[tid];
  }
}

// ---------------------------------------------------------------------------
extern "C" void kernel_launch(void* const* d_in, const int* in_sizes, int n_in,
                              void* d_out, int out_size, void* d_ws, size_t ws_size,
                              hipStream_t stream) {
  (void)in_sizes; (void)n_in; (void)out_size; (void)ws_size;
  const float* x    = (const float*)d_in[0];
  const float* key  = (const float*)d_in[1];
  const float* Wih  = (const float*)d_in[2];
  const float* Whh  = (const float*)d_in[3];
  const float* bih  = (const float*)d_in[4];
  const float* bhh  = (const float*)d_in[5];
  const float* Wcls = (const float*)d_in[6];
  const float* bcls = (const float*)d_in[7];
  float* out = (float*)d_out;

  char* ws = (char*)d_ws;
  size_t off = 0;
  uint32_t* xpk  = (uint32_t*)(ws + off); off += (size_t)BB * TT * 512 * 4;   // 268 MB
  uint4* wreg    = (uint4*)(ws + off);    off += (size_t)6 * 8 * 8 * 64 * 16; // 384 KB
  uint4* wldsG   = (uint4*)(ws + off);    off += (size_t)2 * 8 * 8 * 64 * 16; // 128 KB
  _Float16* WcT  = (_Float16*)(ws + off); off += (size_t)G4 * II * 2;
  float* biasc   = (float*)(ws + off);    off += (size_t)G4 * 4;
  float* hfin    = (float*)(ws + off);    off += (size_t)BB * HH * 4;

  hipLaunchKernelGGL(prep_wc,   dim3(II),  dim3(G4),  0, stream, key, Wih, bih, bhh, WcT, biasc);
  hipLaunchKernelGGL(prep_wfrag, dim3(128), dim3(256), 0, stream, Whh, wreg, wldsG);
  hipLaunchKernelGGL(gemm_xproj, dim3(G4 / 128, (BB * TT) / 128), dim3(256), 0, stream,
                     x, WcT, biasc, (_Float16*)xpk);
  hipLaunchKernelGGL(lstm_seq, dim3(BB), dim3(512), 0, stream,
                     xpk, wreg, wldsG, hfin);
  hipLaunchKernelGGL(cls_k,    dim3(BB), dim3(256), 0, stream, hfin, Wcls, bcls, out);
}